// Round 2
// baseline (226.857 us; speedup 1.0000x reference)
//
#include <hip/hip_runtime.h>
#include <hip/hip_bf16.h>

typedef __bf16  bf16x8 __attribute__((ext_vector_type(8)));
typedef float   f32x4  __attribute__((ext_vector_type(4)));

// XOR swizzle: spreads 256B-stride rows across LDS banks (guide §6 G4)
#define SWZ(b, r) ((b) ^ (((r) & 7) << 4))

// ---------------------------------------------------------------------------
// Kernel A: y[N][128] (bf16) = x[N][128] @ W1[:128][:]   (no bias, no act)
// ---------------------------------------------------------------------------
extern "C" __global__ __launch_bounds__(256)
void gemm_y_kernel(const float* __restrict__ x, const float* __restrict__ W1,
                   __bf16* __restrict__ y, int N)
{
    __shared__ __align__(16) unsigned char ldsW[32768];   // W1a^T bf16 [n][k], swizzled

    const int t = threadIdx.x;
    {   // transpose-stage W1[:128][:] -> ldsW[n][k] (bf16, swizzled)
        const int k  = t >> 1;
        const int n0 = (t & 1) * 64;
        const float* src = W1 + k * 128 + n0;
        #pragma unroll
        for (int j = 0; j < 64; j += 4) {
            float4 v = *(const float4*)(src + j);
            float vv[4] = {v.x, v.y, v.z, v.w};
            #pragma unroll
            for (int i = 0; i < 4; ++i) {
                int n = n0 + j + i;
                *(__bf16*)(ldsW + SWZ(n * 256 + k * 2, n)) = (__bf16)vv[i];
            }
        }
    }
    __syncthreads();

    const int lane = t & 63, w = t >> 6;
    const int laneM = lane & 15, ksub = lane >> 4;
    const int r0 = blockIdx.x * 64 + w * 16;
    const int arow = r0 + laneM;
    const bool av = arow < N;
    const float* xr = x + (size_t)(av ? arow : 0) * 128;

    f32x4 acc[8];
    #pragma unroll
    for (int nt = 0; nt < 8; ++nt) acc[nt] = f32x4{0.f, 0.f, 0.f, 0.f};

    #pragma unroll
    for (int kk = 0; kk < 4; ++kk) {
        bf16x8 a;
        if (av) {
            const float* p = xr + kk * 32 + ksub * 8;
            float4 v0 = *(const float4*)(p);
            float4 v1 = *(const float4*)(p + 4);
            a[0] = (__bf16)v0.x; a[1] = (__bf16)v0.y; a[2] = (__bf16)v0.z; a[3] = (__bf16)v0.w;
            a[4] = (__bf16)v1.x; a[5] = (__bf16)v1.y; a[6] = (__bf16)v1.z; a[7] = (__bf16)v1.w;
        } else {
            #pragma unroll
            for (int e = 0; e < 8; ++e) a[e] = (__bf16)0.f;
        }
        #pragma unroll
        for (int nt = 0; nt < 8; ++nt) {
            const int n = nt * 16 + laneM;
            bf16x8 b = *(const bf16x8*)(ldsW + SWZ(n * 256 + kk * 64 + ksub * 16, n));
            acc[nt] = __builtin_amdgcn_mfma_f32_16x16x32_bf16(a, b, acc[nt], 0, 0, 0);
        }
    }

    // D layout: col = lane&15, row = (lane>>4)*4 + reg   [m89/m91]
    #pragma unroll
    for (int nt = 0; nt < 8; ++nt) {
        const int col = nt * 16 + laneM;
        #pragma unroll
        for (int i = 0; i < 4; ++i) {
            const int rr = r0 + ksub * 4 + i;
            if (rr < N) y[(size_t)rr * 128 + col] = (__bf16)acc[nt][i];
        }
    }
}

// ---------------------------------------------------------------------------
// Kernel B: per 64-row tile: h1 = leaky(y[idx] + xyz@W1b + b1); h2 = h1@W2;
//           out[p] = max over 8 rows + b2
// ---------------------------------------------------------------------------
extern "C" __global__ __launch_bounds__(256)
void conv_kernel(const __bf16* __restrict__ y, const int* __restrict__ idx,
                 const float* __restrict__ xyz, const float* __restrict__ W1,
                 const float* __restrict__ b1, const float* __restrict__ W2,
                 const float* __restrict__ b2, float* __restrict__ out,
                 int ntiles)
{
    __shared__ __align__(16) unsigned char ldsW[32768];  // W2^T bf16 [n][k], swizzled
    __shared__ __align__(16) unsigned char ldsA[16384];  // h1 bf16 [64][128], swizzled
    __shared__ float lW1b[3][128];
    __shared__ float lb1[128];
    __shared__ float lb2[128];

    const int t = threadIdx.x;
    {   // transpose-stage W2 -> ldsW[n][k] (bf16, swizzled) — once per block
        const int k  = t >> 1;
        const int n0 = (t & 1) * 64;
        const float* src = W2 + k * 128 + n0;
        #pragma unroll
        for (int j = 0; j < 64; j += 4) {
            float4 v = *(const float4*)(src + j);
            float vv[4] = {v.x, v.y, v.z, v.w};
            #pragma unroll
            for (int i = 0; i < 4; ++i) {
                int n = n0 + j + i;
                *(__bf16*)(ldsW + SWZ(n * 256 + k * 2, n)) = (__bf16)vv[i];
            }
        }
    }
    if (t < 128) {
        lb1[t] = b1[t];
        lb2[t] = b2[t];
        lW1b[0][t] = W1[128 * 128 + t];
        lW1b[1][t] = W1[129 * 128 + t];
        lW1b[2][t] = W1[130 * 128 + t];
    }
    __syncthreads();

    const int lane = t & 63, w = t >> 6;
    const int laneM = lane & 15, ksub = lane >> 4;
    const int sr = t >> 2, spart = t & 3;     // staging: row 0..63, quarter 0..3

    for (int tile = blockIdx.x; tile < ntiles; tile += gridDim.x) {
        const int m0 = tile * 64;
        // ---- stage h1 (fused gather + rank-3 xyz update + bias + leaky) ----
        {
            const int m = m0 + sr;
            const int gi = idx[m];
            const float q0 = xyz[m * 3 + 0], q1 = xyz[m * 3 + 1], q2 = xyz[m * 3 + 2];
            const __bf16* yr = y + (size_t)gi * 128 + spart * 32;
            #pragma unroll
            for (int j = 0; j < 4; ++j) {
                bf16x8 v = *(const bf16x8*)(yr + j * 8);
                const int cb = spart * 32 + j * 8;
                bf16x8 o;
                #pragma unroll
                for (int e = 0; e < 8; ++e) {
                    const int c = cb + e;
                    float h = (float)v[e] + q0 * lW1b[0][c] + q1 * lW1b[1][c]
                              + q2 * lW1b[2][c] + lb1[c];
                    h = h > 0.f ? h : 0.01f * h;
                    o[e] = (__bf16)h;
                }
                *(bf16x8*)(ldsA + SWZ(sr * 256 + cb * 2, sr)) = o;
            }
        }
        __syncthreads();
        // ---- layer-2 GEMM: wave w owns rows w*16..w*16+15, all 128 cols ----
        f32x4 acc[8];
        #pragma unroll
        for (int nt = 0; nt < 8; ++nt) acc[nt] = f32x4{0.f, 0.f, 0.f, 0.f};
        #pragma unroll
        for (int kk = 0; kk < 4; ++kk) {
            const int row = w * 16 + laneM;
            bf16x8 a = *(const bf16x8*)(ldsA + SWZ(row * 256 + kk * 64 + ksub * 16, row));
            #pragma unroll
            for (int nt = 0; nt < 8; ++nt) {
                const int n = nt * 16 + laneM;
                bf16x8 b = *(const bf16x8*)(ldsW + SWZ(n * 256 + kk * 64 + ksub * 16, n));
                acc[nt] = __builtin_amdgcn_mfma_f32_16x16x32_bf16(a, b, acc[nt], 0, 0, 0);
            }
        }
        // ---- max-pool over 8 rows + bias (bias added AFTER max: row-invariant) ----
        const int p0 = tile * 8 + w * 2;   // wave covers output points p0, p0+1
        #pragma unroll
        for (int nt = 0; nt < 8; ++nt) {
            float m4 = fmaxf(fmaxf(acc[nt][0], acc[nt][1]), fmaxf(acc[nt][2], acc[nt][3]));
            float mm = fmaxf(m4, __shfl_xor(m4, 16));
            const int col = nt * 16 + laneM;
            if (ksub == 0)      out[(size_t)p0 * 128 + col]       = mm + lb2[col];
            else if (ksub == 2) out[(size_t)(p0 + 1) * 128 + col] = mm + lb2[col];
        }
        __syncthreads();   // protect ldsA before next tile's staging
    }
}

// ---------------------------------------------------------------------------
extern "C" void kernel_launch(void* const* d_in, const int* in_sizes, int n_in,
                              void* d_out, int out_size, void* d_ws, size_t ws_size,
                              hipStream_t stream)
{
    const float* x    = (const float*)d_in[0];
    const int*   kidx = (const int*)d_in[1];
    const float* kxyz = (const float*)d_in[2];
    const float* W1   = (const float*)d_in[3];
    const float* b1   = (const float*)d_in[4];
    const float* W2   = (const float*)d_in[5];
    const float* b2   = (const float*)d_in[6];
    float* out = (float*)d_out;

    const int N = in_sizes[0] / 128;     // 100000 points
    const int M = in_sizes[1];           // 800000 gather rows
    const int ntiles = M / 64;           // 12500 (exact)

    __bf16* y = (__bf16*)d_ws;           // y[N][128] bf16 = x @ W1[:128]

    hipLaunchKernelGGL(gemm_y_kernel, dim3((N + 63) / 64), dim3(256), 0, stream,
                       x, W1, y, N);

    const int grid = ntiles < 768 ? ntiles : 768;   // persistent: 3 blocks/CU (LDS-limited)
    hipLaunchKernelGGL(conv_kernel, dim3(grid), dim3(256), 0, stream,
                       y, kidx, kxyz, W1, b1, W2, b2, out, ntiles);
}

// Round 4
// 192.274 us; speedup vs baseline: 1.1799x; 1.1799x over previous
//
#include <hip/hip_runtime.h>
#include <hip/hip_bf16.h>

typedef __bf16  bf16x8 __attribute__((ext_vector_type(8)));
typedef float   f32x4  __attribute__((ext_vector_type(4)));

// XOR swizzle: spreads 256B-stride rows across LDS banks (guide §6 G4)
#define SWZ(b, r) ((b) ^ (((r) & 7) << 4))

// ---------------------------------------------------------------------------
// Kernel A: y[N][128] (bf16) = x[N][128] @ W1[:128][:]
// Persistent: W1^T staged to LDS once per block, grid-stride over 64-row tiles.
// ---------------------------------------------------------------------------
extern "C" __global__ __launch_bounds__(256)
void gemm_y_kernel(const float* __restrict__ x, const float* __restrict__ W1,
                   __bf16* __restrict__ y, int N, int ntiles)
{
    __shared__ __align__(16) unsigned char ldsW[32768];   // W1a^T bf16 [n][k], swizzled

    const int t = threadIdx.x;
    {   // transpose-stage W1[:128][:] -> ldsW[n][k] (bf16, swizzled) — once per block
        const int k  = t >> 1;
        const int n0 = (t & 1) * 64;
        const float* src = W1 + k * 128 + n0;
        #pragma unroll
        for (int j = 0; j < 64; j += 4) {
            float4 v = *(const float4*)(src + j);
            float vv[4] = {v.x, v.y, v.z, v.w};
            #pragma unroll
            for (int i = 0; i < 4; ++i) {
                int n = n0 + j + i;
                *(__bf16*)(ldsW + SWZ(n * 256 + k * 2, n)) = (__bf16)vv[i];
            }
        }
    }
    __syncthreads();

    const int lane = t & 63, w = t >> 6;
    const int laneM = lane & 15, ksub = lane >> 4;

    for (int tile = blockIdx.x; tile < ntiles; tile += gridDim.x) {
        const int r0 = tile * 64 + w * 16;
        const int arow = r0 + laneM;
        const bool av = arow < N;
        const float* xr = x + (size_t)(av ? arow : 0) * 128;

        f32x4 acc[8];
        #pragma unroll
        for (int nt = 0; nt < 8; ++nt) acc[nt] = f32x4{0.f, 0.f, 0.f, 0.f};

        #pragma unroll
        for (int kk = 0; kk < 4; ++kk) {
            bf16x8 a;
            if (av) {
                const float* p = xr + kk * 32 + ksub * 8;
                float4 v0 = *(const float4*)(p);
                float4 v1 = *(const float4*)(p + 4);
                a[0] = (__bf16)v0.x; a[1] = (__bf16)v0.y; a[2] = (__bf16)v0.z; a[3] = (__bf16)v0.w;
                a[4] = (__bf16)v1.x; a[5] = (__bf16)v1.y; a[6] = (__bf16)v1.z; a[7] = (__bf16)v1.w;
            } else {
                #pragma unroll
                for (int e = 0; e < 8; ++e) a[e] = (__bf16)0.f;
            }
            #pragma unroll
            for (int nt = 0; nt < 8; ++nt) {
                const int n = nt * 16 + laneM;
                bf16x8 b = *(const bf16x8*)(ldsW + SWZ(n * 256 + kk * 64 + ksub * 16, n));
                acc[nt] = __builtin_amdgcn_mfma_f32_16x16x32_bf16(a, b, acc[nt], 0, 0, 0);
            }
        }

        // D layout: col = lane&15, row = (lane>>4)*4 + reg   [m89/m91]
        #pragma unroll
        for (int nt = 0; nt < 8; ++nt) {
            const int col = nt * 16 + laneM;
            #pragma unroll
            for (int i = 0; i < 4; ++i) {
                const int rr = r0 + ksub * 4 + i;
                if (rr < N) y[(size_t)rr * 128 + col] = (__bf16)acc[nt][i];
            }
        }
        __syncthreads();   // ldsW is read-only after stage; barrier only orders tile reuse (cheap)
    }
}

// ---------------------------------------------------------------------------
// Kernel B: per 64-row tile: h1 = leaky(y[idx] + xyz@W1b + b1); h2 = h1@W2;
//           out[p] = max over 8 rows + b2
// Staging: thread = (rgroup = t>>4 -> rows rgroup*4..+3, cslot = t&15 -> cols
// cslot*8..+7). W1b/b1 column slices live in 32 VGPRs (loop-invariant per
// thread) — zero per-tile LDS table reads (was 4-way-conflicted, 3.6K cyc/tile).
// ---------------------------------------------------------------------------
extern "C" __global__ __launch_bounds__(256, 3)
void conv_kernel(const __bf16* __restrict__ y, const int* __restrict__ idx,
                 const float* __restrict__ xyz, const float* __restrict__ W1,
                 const float* __restrict__ b1, const float* __restrict__ W2,
                 const float* __restrict__ b2, float* __restrict__ out,
                 int ntiles)
{
    __shared__ __align__(16) unsigned char ldsW[32768];  // W2^T bf16 [n][k], swizzled
    __shared__ __align__(16) unsigned char ldsA[16384];  // h1 bf16 [64][128], swizzled

    const int t = threadIdx.x;
    {   // transpose-stage W2 -> ldsW[n][k] (bf16, swizzled) — once per block
        const int k  = t >> 1;
        const int n0 = (t & 1) * 64;
        const float* src = W2 + k * 128 + n0;
        #pragma unroll
        for (int j = 0; j < 64; j += 4) {
            float4 v = *(const float4*)(src + j);
            float vv[4] = {v.x, v.y, v.z, v.w};
            #pragma unroll
            for (int i = 0; i < 4; ++i) {
                int n = n0 + j + i;
                *(__bf16*)(ldsW + SWZ(n * 256 + k * 2, n)) = (__bf16)vv[i];
            }
        }
    }

    const int lane = t & 63, w = t >> 6;
    const int laneM = lane & 15, ksub = lane >> 4;
    const int cslot = t & 15, rgroup = t >> 4;
    const int c0 = cslot * 8;

    // Register tables: W1b rows / b1 for this thread's fixed 8-col slice.
    float wA[8], wB[8], wC[8], bb[8];
    {
        float4 u, v;
        u = *(const float4*)(W1 + 128 * 128 + c0); v = *(const float4*)(W1 + 128 * 128 + c0 + 4);
        wA[0]=u.x; wA[1]=u.y; wA[2]=u.z; wA[3]=u.w; wA[4]=v.x; wA[5]=v.y; wA[6]=v.z; wA[7]=v.w;
        u = *(const float4*)(W1 + 129 * 128 + c0); v = *(const float4*)(W1 + 129 * 128 + c0 + 4);
        wB[0]=u.x; wB[1]=u.y; wB[2]=u.z; wB[3]=u.w; wB[4]=v.x; wB[5]=v.y; wB[6]=v.z; wB[7]=v.w;
        u = *(const float4*)(W1 + 130 * 128 + c0); v = *(const float4*)(W1 + 130 * 128 + c0 + 4);
        wC[0]=u.x; wC[1]=u.y; wC[2]=u.z; wC[3]=u.w; wC[4]=v.x; wC[5]=v.y; wC[6]=v.z; wC[7]=v.w;
        u = *(const float4*)(b1 + c0);             v = *(const float4*)(b1 + c0 + 4);
        bb[0]=u.x; bb[1]=u.y; bb[2]=u.z; bb[3]=u.w; bb[4]=v.x; bb[5]=v.y; bb[6]=v.z; bb[7]=v.w;
    }
    // b2 slice for the output stage (col = nt*16 + laneM)
    float b2r[8];
    #pragma unroll
    for (int nt = 0; nt < 8; ++nt) b2r[nt] = b2[nt * 16 + laneM];

    __syncthreads();

    for (int tile = blockIdx.x; tile < ntiles; tile += gridDim.x) {
        const int m0 = tile * 64;
        // ---- stage h1: gather y rows + rank-3 xyz update + bias + leaky ----
        {
            const int mr = m0 + rgroup * 4;
            int4   gi4 = *(const int4*)(idx + mr);
            float4 xa  = *(const float4*)(xyz + (size_t)mr * 3);
            float4 xb  = *(const float4*)(xyz + (size_t)mr * 3 + 4);
            float4 xc  = *(const float4*)(xyz + (size_t)mr * 3 + 8);
            const float qv[12] = {xa.x, xa.y, xa.z, xa.w, xb.x, xb.y, xb.z, xb.w,
                                  xc.x, xc.y, xc.z, xc.w};
            const int gis[4] = {gi4.x, gi4.y, gi4.z, gi4.w};
            bf16x8 vv[4];
            #pragma unroll
            for (int q = 0; q < 4; ++q)       // 4 independent gathers in flight
                vv[q] = *(const bf16x8*)(y + (size_t)gis[q] * 128 + c0);
            #pragma unroll
            for (int q = 0; q < 4; ++q) {
                const int r = rgroup * 4 + q;
                const float q0 = qv[3 * q], q1 = qv[3 * q + 1], q2 = qv[3 * q + 2];
                bf16x8 o;
                #pragma unroll
                for (int e = 0; e < 8; ++e) {
                    float h = (float)vv[q][e] + q0 * wA[e] + q1 * wB[e] + q2 * wC[e] + bb[e];
                    h = fmaxf(h, 0.01f * h);              // leaky_relu(0.01)
                    o[e] = (__bf16)h;
                }
                *(bf16x8*)(ldsA + SWZ(r * 256 + c0 * 2, r)) = o;
            }
        }
        __syncthreads();
        // ---- layer-2 GEMM: wave w owns rows w*16..w*16+15, all 128 cols ----
        f32x4 acc[8];
        #pragma unroll
        for (int nt = 0; nt < 8; ++nt) acc[nt] = f32x4{0.f, 0.f, 0.f, 0.f};
        #pragma unroll
        for (int kk = 0; kk < 4; ++kk) {
            const int row = w * 16 + laneM;
            bf16x8 a = *(const bf16x8*)(ldsA + SWZ(row * 256 + kk * 64 + ksub * 16, row));
            #pragma unroll
            for (int nt = 0; nt < 8; ++nt) {
                const int n = nt * 16 + laneM;
                bf16x8 b = *(const bf16x8*)(ldsW + SWZ(n * 256 + kk * 64 + ksub * 16, n));
                acc[nt] = __builtin_amdgcn_mfma_f32_16x16x32_bf16(a, b, acc[nt], 0, 0, 0);
            }
        }
        // ---- max-pool over 8 rows + bias (bias added AFTER max: row-invariant) ----
        const int p0 = tile * 8 + w * 2;   // wave covers output points p0, p0+1
        #pragma unroll
        for (int nt = 0; nt < 8; ++nt) {
            float m4 = fmaxf(fmaxf(acc[nt][0], acc[nt][1]), fmaxf(acc[nt][2], acc[nt][3]));
            float mm = fmaxf(m4, __shfl_xor(m4, 16));
            const int col = nt * 16 + laneM;
            if (ksub == 0)      out[(size_t)p0 * 128 + col]       = mm + b2r[nt];
            else if (ksub == 2) out[(size_t)(p0 + 1) * 128 + col] = mm + b2r[nt];
        }
        __syncthreads();   // protect ldsA before next tile's staging
    }
}

// ---------------------------------------------------------------------------
extern "C" void kernel_launch(void* const* d_in, const int* in_sizes, int n_in,
                              void* d_out, int out_size, void* d_ws, size_t ws_size,
                              hipStream_t stream)
{
    const float* x    = (const float*)d_in[0];
    const int*   kidx = (const int*)d_in[1];
    const float* kxyz = (const float*)d_in[2];
    const float* W1   = (const float*)d_in[3];
    const float* b1   = (const float*)d_in[4];
    const float* W2   = (const float*)d_in[5];
    const float* b2   = (const float*)d_in[6];
    float* out = (float*)d_out;

    const int N = in_sizes[0] / 128;     // 100000 points
    const int M = in_sizes[1];           // 800000 gather rows
    const int ntiles  = M / 64;          // 12500 (exact)
    const int ntilesA = (N + 63) / 64;   // 1563

    __bf16* y = (__bf16*)d_ws;           // y[N][128] bf16 = x @ W1[:128]

    const int gridA = ntilesA < 768 ? ntilesA : 768;
    hipLaunchKernelGGL(gemm_y_kernel, dim3(gridA), dim3(256), 0, stream,
                       x, W1, y, N, ntilesA);

    const int grid = ntiles < 768 ? ntiles : 768;   // persistent: 3 blocks/CU (LDS-limited)
    hipLaunchKernelGGL(conv_kernel, dim3(grid), dim3(256), 0, stream,
                       y, kidx, kxyz, W1, b1, W2, b2, out, ntiles);
}

// Round 7
// 182.369 us; speedup vs baseline: 1.2439x; 1.0543x over previous
//
#include <hip/hip_runtime.h>
#include <hip/hip_bf16.h>

typedef __bf16  bf16x8 __attribute__((ext_vector_type(8)));
typedef float   f32x4  __attribute__((ext_vector_type(4)));

// XOR swizzle: spreads 256B-stride rows across LDS banks (guide §6 G4)
#define SWZ(b, r) ((b) ^ (((r) & 7) << 4))

// lgkmcnt(0)+raw barrier: orders LDS writes/reads across waves WITHOUT the
// vmcnt(0) drain __syncthreads emits — keeps prefetch gathers in flight (T3/T4).
#define BAR() do { asm volatile("s_waitcnt lgkmcnt(0)" ::: "memory"); \
                   __builtin_amdgcn_s_barrier(); } while (0)

// ---------------------------------------------------------------------------
// Kernel A: y[N][128] (bf16) = x[N][128] @ W1[:128][:]
// Persistent: W1^T staged to LDS once per block, grid-stride over 64-row tiles.
// ---------------------------------------------------------------------------
extern "C" __global__ __launch_bounds__(256)
void gemm_y_kernel(const float* __restrict__ x, const float* __restrict__ W1,
                   __bf16* __restrict__ y, int N, int ntiles)
{
    __shared__ __align__(16) unsigned char ldsW[32768];   // W1a^T bf16 [n][k], swizzled

    const int t = threadIdx.x;
    {   // transpose-stage W1[:128][:] -> ldsW[n][k] (bf16, swizzled) — once per block
        const int k  = t >> 1;
        const int n0 = (t & 1) * 64;
        const float* src = W1 + k * 128 + n0;
        #pragma unroll
        for (int j = 0; j < 64; j += 4) {
            float4 v = *(const float4*)(src + j);
            float vv[4] = {v.x, v.y, v.z, v.w};
            #pragma unroll
            for (int i = 0; i < 4; ++i) {
                int n = n0 + j + i;
                *(__bf16*)(ldsW + SWZ(n * 256 + k * 2, n)) = (__bf16)vv[i];
            }
        }
    }
    __syncthreads();

    const int lane = t & 63, w = t >> 6;
    const int laneM = lane & 15, ksub = lane >> 4;

    for (int tile = blockIdx.x; tile < ntiles; tile += gridDim.x) {
        const int r0 = tile * 64 + w * 16;
        const int arow = r0 + laneM;
        const bool av = arow < N;
        const float* xr = x + (size_t)(av ? arow : 0) * 128;

        f32x4 acc[8];
        #pragma unroll
        for (int nt = 0; nt < 8; ++nt) acc[nt] = f32x4{0.f, 0.f, 0.f, 0.f};

        #pragma unroll
        for (int kk = 0; kk < 4; ++kk) {
            bf16x8 a;
            if (av) {
                const float* p = xr + kk * 32 + ksub * 8;
                float4 v0 = *(const float4*)(p);
                float4 v1 = *(const float4*)(p + 4);
                a[0] = (__bf16)v0.x; a[1] = (__bf16)v0.y; a[2] = (__bf16)v0.z; a[3] = (__bf16)v0.w;
                a[4] = (__bf16)v1.x; a[5] = (__bf16)v1.y; a[6] = (__bf16)v1.z; a[7] = (__bf16)v1.w;
            } else {
                #pragma unroll
                for (int e = 0; e < 8; ++e) a[e] = (__bf16)0.f;
            }
            #pragma unroll
            for (int nt = 0; nt < 8; ++nt) {
                const int n = nt * 16 + laneM;
                bf16x8 b = *(const bf16x8*)(ldsW + SWZ(n * 256 + kk * 64 + ksub * 16, n));
                acc[nt] = __builtin_amdgcn_mfma_f32_16x16x32_bf16(a, b, acc[nt], 0, 0, 0);
            }
        }

        // D layout: col = lane&15, row = (lane>>4)*4 + reg   [m89/m91]
        #pragma unroll
        for (int nt = 0; nt < 8; ++nt) {
            const int col = nt * 16 + laneM;
            #pragma unroll
            for (int i = 0; i < 4; ++i) {
                const int rr = r0 + ksub * 4 + i;
                if (rr < N) y[(size_t)rr * 128 + col] = (__bf16)acc[nt][i];
            }
        }
        __syncthreads();
    }
}

// ---------------------------------------------------------------------------
// Kernel B — pipelined: per 64-row tile:
//   h1 = leaky(y[idx] + xyz@W1b + b1)  -> LDS (double-buffered, XOR-swizzled)
//   h2 = h1 @ W2 (W2 fragments live in 32 VGPRs/wave; wave owns 64r x 32c)
//   out[p] = max over 8 rows + b2
// 2-deep prefetch: y-gather 1 tile ahead, idx/xyz 2 tiles ahead; raw barrier
// (no vmcnt drain) keeps prefetches in flight across the per-tile barrier.
// ---------------------------------------------------------------------------
extern "C" __global__ __launch_bounds__(256, 2)
void conv_kernel(const __bf16* __restrict__ y, const int* __restrict__ idx,
                 const float* __restrict__ xyz, const float* __restrict__ W1,
                 const float* __restrict__ b1, const float* __restrict__ W2,
                 const float* __restrict__ b2, float* __restrict__ out,
                 int ntiles)
{
    // Union: first W2^T staging (32 KB), then h1 double-buffer (2 x 16 KB).
    __shared__ __align__(16) unsigned char lds[32768];

    const int t = threadIdx.x;
    const int lane = t & 63, w = t >> 6;
    const int laneM = lane & 15, ksub = lane >> 4;
    const int cslot = t & 15, rgroup = t >> 4;
    const int c0 = cslot * 8;

    {   // transpose-stage W2 -> lds[n][k] (bf16, swizzled) — once per block
        const int k  = t >> 1;
        const int n0 = (t & 1) * 64;
        const float* src = W2 + k * 128 + n0;
        #pragma unroll
        for (int j = 0; j < 64; j += 4) {
            float4 v = *(const float4*)(src + j);
            float vv[4] = {v.x, v.y, v.z, v.w};
            #pragma unroll
            for (int i = 0; i < 4; ++i) {
                int n = n0 + j + i;
                *(__bf16*)(lds + SWZ(n * 256 + k * 2, n)) = (__bf16)vv[i];
            }
        }
    }
    __syncthreads();
    // B-fragments for this wave's 32-col slice -> registers (held all kernel)
    bf16x8 Bf0[4], Bf1[4];
    #pragma unroll
    for (int kk = 0; kk < 4; ++kk) {
        const int n0 = w * 32 + laneM;
        const int n1 = n0 + 16;
        Bf0[kk] = *(const bf16x8*)(lds + SWZ(n0 * 256 + kk * 64 + ksub * 16, n0));
        Bf1[kk] = *(const bf16x8*)(lds + SWZ(n1 * 256 + kk * 64 + ksub * 16, n1));
    }
    __syncthreads();   // all waves done reading W2 before lds is reused for h1

    // Register tables: W1b rows / b1 for this thread's fixed 8-col slice.
    float wA[8], wB[8], wC[8], bb[8];
    {
        float4 u, v;
        u = *(const float4*)(W1 + 128 * 128 + c0); v = *(const float4*)(W1 + 128 * 128 + c0 + 4);
        wA[0]=u.x; wA[1]=u.y; wA[2]=u.z; wA[3]=u.w; wA[4]=v.x; wA[5]=v.y; wA[6]=v.z; wA[7]=v.w;
        u = *(const float4*)(W1 + 129 * 128 + c0); v = *(const float4*)(W1 + 129 * 128 + c0 + 4);
        wB[0]=u.x; wB[1]=u.y; wB[2]=u.z; wB[3]=u.w; wB[4]=v.x; wB[5]=v.y; wB[6]=v.z; wB[7]=v.w;
        u = *(const float4*)(W1 + 130 * 128 + c0); v = *(const float4*)(W1 + 130 * 128 + c0 + 4);
        wC[0]=u.x; wC[1]=u.y; wC[2]=u.z; wC[3]=u.w; wC[4]=v.x; wC[5]=v.y; wC[6]=v.z; wC[7]=v.w;
        u = *(const float4*)(b1 + c0);             v = *(const float4*)(b1 + c0 + 4);
        bb[0]=u.x; bb[1]=u.y; bb[2]=u.z; bb[3]=u.w; bb[4]=v.x; bb[5]=v.y; bb[6]=v.z; bb[7]=v.w;
    }
    float b2r[2];
    b2r[0] = b2[w * 32 + laneM];
    b2r[1] = b2[w * 32 + 16 + laneM];

#define ISSUE_IDX(TT, GI, X0, X1, X2)                                          \
    { int tt_ = (TT); if (tt_ >= ntiles) tt_ = 0;                              \
      const int mr_ = tt_ * 64 + rgroup * 4;                                   \
      GI = *(const int4*)(idx + mr_);                                          \
      X0 = *(const float4*)(xyz + (size_t)mr_ * 3);                            \
      X1 = *(const float4*)(xyz + (size_t)mr_ * 3 + 4);                        \
      X2 = *(const float4*)(xyz + (size_t)mr_ * 3 + 8); }

#define ISSUE_GATHER(GI, YV)                                                   \
    { YV[0] = *(const bf16x8*)(y + (size_t)(GI).x * 128 + c0);                 \
      YV[1] = *(const bf16x8*)(y + (size_t)(GI).y * 128 + c0);                 \
      YV[2] = *(const bf16x8*)(y + (size_t)(GI).z * 128 + c0);                 \
      YV[3] = *(const bf16x8*)(y + (size_t)(GI).w * 128 + c0); }

#define EPILOGUE(YV, X0, X1, X2, BOFF)                                         \
    { const float q_[12] = {X0.x, X0.y, X0.z, X0.w, X1.x, X1.y, X1.z, X1.w,    \
                            X2.x, X2.y, X2.z, X2.w};                           \
      _Pragma("unroll")                                                        \
      for (int q = 0; q < 4; ++q) {                                            \
        const int r_ = rgroup * 4 + q;                                         \
        const float q0 = q_[3*q], q1 = q_[3*q+1], q2 = q_[3*q+2];              \
        bf16x8 o;                                                              \
        _Pragma("unroll")                                                      \
        for (int e = 0; e < 8; ++e) {                                          \
          float h = (float)YV[q][e] + q0*wA[e] + q1*wB[e] + q2*wC[e] + bb[e];  \
          h = fmaxf(h, 0.01f * h);                                             \
          o[e] = (__bf16)h;                                                    \
        }                                                                      \
        *(bf16x8*)(lds + (BOFF) + SWZ(r_ * 256 + c0 * 2, r_)) = o;             \
      } }

#define GEMM_STORE(BOFF, TILE)                                                 \
    { f32x4 acc[4][2];                                                         \
      _Pragma("unroll")                                                        \
      for (int mt = 0; mt < 4; ++mt) {                                         \
        acc[mt][0] = f32x4{0.f,0.f,0.f,0.f};                                   \
        acc[mt][1] = f32x4{0.f,0.f,0.f,0.f};                                   \
      }                                                                        \
      __builtin_amdgcn_s_setprio(1);                                           \
      _Pragma("unroll")                                                        \
      for (int kk = 0; kk < 4; ++kk) {                                         \
        _Pragma("unroll")                                                      \
        for (int mt = 0; mt < 4; ++mt) {                                       \
          const int row_ = mt * 16 + laneM;                                    \
          bf16x8 a = *(const bf16x8*)(lds + (BOFF) +                           \
                        SWZ(row_ * 256 + kk * 64 + ksub * 16, row_));          \
          acc[mt][0] = __builtin_amdgcn_mfma_f32_16x16x32_bf16(a, Bf0[kk], acc[mt][0], 0,0,0); \
          acc[mt][1] = __builtin_amdgcn_mfma_f32_16x16x32_bf16(a, Bf1[kk], acc[mt][1], 0,0,0); \
        }                                                                      \
      }                                                                        \
      __builtin_amdgcn_s_setprio(0);                                           \
      const int p0_ = (TILE) * 8;                                              \
      _Pragma("unroll")                                                        \
      for (int mt = 0; mt < 4; ++mt) {                                         \
        _Pragma("unroll")                                                      \
        for (int nt = 0; nt < 2; ++nt) {                                       \
          float m4 = fmaxf(fmaxf(acc[mt][nt][0], acc[mt][nt][1]),              \
                           fmaxf(acc[mt][nt][2], acc[mt][nt][3]));             \
          float mm = fmaxf(m4, __shfl_xor(m4, 16));                            \
          const int col_ = w * 32 + nt * 16 + laneM;                           \
          if (!(ksub & 1))                                                     \
            out[(size_t)(p0_ + mt * 2 + (ksub >> 1)) * 128 + col_] = mm + b2r[nt]; \
        }                                                                      \
      } }

    const int G_  = gridDim.x;
    const int bid = blockIdx.x;
    const int cnt = (ntiles - bid + G_ - 1) / G_;   // tiles for this block

    int4 giA, giB;
    float4 xaA, xbA, xcA, xaB, xbB, xcB;
    bf16x8 yvA[4], yvB[4];

    // prologue: set A = tile bid, set B = tile bid+G
    ISSUE_IDX(bid, giA, xaA, xbA, xcA);
    ISSUE_IDX(bid + G_, giB, xaB, xbB, xcB);
    ISSUE_GATHER(giA, yvA);

    int T = bid;
    int k = 0;
    for (; k + 1 < cnt; k += 2, T += 2 * G_) {
        // ---- half A: tile T -> buf 0 ----
        ISSUE_GATHER(giB, yvB);                         // y rows for tile T+G
        EPILOGUE(yvA, xaA, xbA, xcA, 0);                // consume set A (waits yvA)
        ISSUE_IDX(T + 2 * G_, giA, xaA, xbA, xcA);      // idx/xyz for tile T+2G
        BAR();
        GEMM_STORE(0, T);
        // ---- half B: tile T+G -> buf 1 ----
        ISSUE_GATHER(giA, yvA);                         // y rows for tile T+2G
        EPILOGUE(yvB, xaB, xbB, xcB, 16384);            // consume set B (waits yvB)
        ISSUE_IDX(T + 3 * G_, giB, xaB, xbB, xcB);      // idx/xyz for tile T+3G
        BAR();
        GEMM_STORE(16384, T + G_);
    }
    if (k < cnt) {                                      // tail: one tile left, set A
        EPILOGUE(yvA, xaA, xbA, xcA, 0);
        BAR();
        GEMM_STORE(0, T);
    }
#undef ISSUE_IDX
#undef ISSUE_GATHER
#undef EPILOGUE
#undef GEMM_STORE
}

// ---------------------------------------------------------------------------
extern "C" void kernel_launch(void* const* d_in, const int* in_sizes, int n_in,
                              void* d_out, int out_size, void* d_ws, size_t ws_size,
                              hipStream_t stream)
{
    const float* x    = (const float*)d_in[0];
    const int*   kidx = (const int*)d_in[1];
    const float* kxyz = (const float*)d_in[2];
    const float* W1   = (const float*)d_in[3];
    const float* b1   = (const float*)d_in[4];
    const float* W2   = (const float*)d_in[5];
    const float* b2   = (const float*)d_in[6];
    float* out = (float*)d_out;

    const int N = in_sizes[0] / 128;     // 100000 points
    const int M = in_sizes[1];           // 800000 gather rows
    const int ntiles  = M / 64;          // 12500 (exact)
    const int ntilesA = (N + 63) / 64;   // 1563

    __bf16* y = (__bf16*)d_ws;           // y[N][128] bf16 = x @ W1[:128]

    const int gridA = ntilesA < 768 ? ntilesA : 768;
    hipLaunchKernelGGL(gemm_y_kernel, dim3(gridA), dim3(256), 0, stream,
                       x, W1, y, N, ntilesA);

    const int grid = ntiles < 512 ? ntiles : 512;   // 2 blocks/CU (VGPR-bound)
    hipLaunchKernelGGL(conv_kernel, dim3(grid), dim3(256), 0, stream,
                       y, kidx, kxyz, W1, b1, W2, b2, out, ntiles);
}